// Round 8
// baseline (10.158 us; speedup 1.0000x reference)
//
#include <hip/hip_runtime.h>

// Simple1DSSM as an adaptively-truncated causal FIR.
// K[m] = sum_d w_d r_d^m, w_d = C_d*Bb_d, r_d = exp(delta*A_d) <= e^-delta (A_d <= -1).
// Grid-uniform tap count M from the exact tail bound:
//   sum_{m>=M}|K[m]| <= sden * e^{-delta*M},  M = ceil((ln(sden)+11.6)/delta), clamped.
// 1024 blocks x 128 threads x 4 outputs/thread (8 blocks/CU, 16 waves/CU).
// Staging loads issued FIRST (fixed 1536 halo, zero-filled past row start), K table
// built under the load shadow, single conv with float4 K + sliding register window.

#define SEQ_L 8192
#define NB    64
#define MCAP  1532
#define HST   1536               // fixed staged halo (>= M4 + 4 always)
#define OUTB  512                // outputs per block
#define XWIN  (HST + OUTB)       // 2048 floats

__global__ __launch_bounds__(128) void ssm_fir(const float* __restrict__ x,
                                               const float* __restrict__ A,
                                               const float* __restrict__ B,
                                               const float* __restrict__ C,
                                               const float* __restrict__ logd,
                                               float* __restrict__ out)
{
    __shared__ __align__(16) float Kl[1536];
    __shared__ __align__(16) float xL[XWIN];
    __shared__ float sW[64], sDA[64];
    __shared__ int   sM;

    const int tid = threadIdx.x;
    const int b   = blockIdx.x >> 4;          // 16 blocks per batch row
    const int t0  = (blockIdx.x & 15) * OUTB; // within-row start
    const float* xb = x + b * SEQ_L;

    // ---- 1) issue x staging loads first: window [t0-HST, t0+OUTB) ----
    float4 st[4];
    #pragma unroll
    for (int i = 0; i < 4; ++i) {
        const int t = t0 - HST + (tid + i * 128) * 4;   // 16B-aligned
        st[i] = make_float4(0.f, 0.f, 0.f, 0.f);
        if (t >= 0) st[i] = *(const float4*)(xb + t);   // zero-fill before row start
    }

    // ---- 2) params + grid-uniform tap count (wave 0), under load shadow ----
    const float delta = __expf(logd[0]);
    if (tid < 64) {
        const float Ad = A[tid];
        const float dA = delta * Ad;
        const float r  = __expf(dA);
        const float w  = C[tid] * (r - 1.f) / Ad * B[tid];
        sW[tid]  = w;
        sDA[tid] = dA;
        float t = fabsf(w) / (1.f - r);
        #pragma unroll
        for (int off = 32; off; off >>= 1) t += __shfl_xor(t, off);
        if (tid == 0) {
            const int M = (int)ceilf((logf(t) + 11.6f) / delta);
            sM = min(max(M, 1), MCAP);
        }
    }

    // ---- 3) write staged x to LDS ----
    #pragma unroll
    for (int i = 0; i < 4; ++i)
        *(float4*)(xL + (tid + i * 128) * 4) = st[i];
    __syncthreads();

    const int M4 = (sM + 3) & ~3;

    // ---- 4) build K[0..M4): 4 threads per tap, 16 d's each, shfl-combine ----
    for (int mb = tid >> 2; mb < M4; mb += 32) {
        const int d0 = (tid & 3) * 16;
        const float fm = (float)mb;
        float s = 0.f;
        #pragma unroll
        for (int dd = 0; dd < 16; ++dd)
            s = fmaf(sW[d0 + dd], __expf(fm * sDA[d0 + dd]), s);
        s += __shfl_xor(s, 1);
        s += __shfl_xor(s, 2);
        if ((tid & 3) == 0) Kl[mb] = s;
    }
    __syncthreads();

    // ---- 5) conv: outputs t0 + tid*4 .. +3 ----
    const int base = HST + tid * 4;
    float4 Wlo = *(const float4*)(xL + base - 4);
    float4 Whi = *(const float4*)(xL + base);
    float a0 = 0.f, a1 = 0.f, a2 = 0.f, a3 = 0.f;
    for (int m0 = 0; m0 < M4; m0 += 4) {
        const float4 Kv = *(const float4*)(Kl + m0);   // wave-uniform broadcast
        a0 = fmaf(Kv.x, Whi.x, a0); a1 = fmaf(Kv.x, Whi.y, a1);
        a2 = fmaf(Kv.x, Whi.z, a2); a3 = fmaf(Kv.x, Whi.w, a3);
        a0 = fmaf(Kv.y, Wlo.w, a0); a1 = fmaf(Kv.y, Whi.x, a1);
        a2 = fmaf(Kv.y, Whi.y, a2); a3 = fmaf(Kv.y, Whi.z, a3);
        a0 = fmaf(Kv.z, Wlo.z, a0); a1 = fmaf(Kv.z, Wlo.w, a1);
        a2 = fmaf(Kv.z, Whi.x, a2); a3 = fmaf(Kv.z, Whi.y, a3);
        a0 = fmaf(Kv.w, Wlo.y, a0); a1 = fmaf(Kv.w, Wlo.z, a1);
        a2 = fmaf(Kv.w, Wlo.w, a2); a3 = fmaf(Kv.w, Whi.x, a3);
        Whi = Wlo;
        Wlo = *(const float4*)(xL + base - m0 - 8);    // >= xL[0]: HST >= M4 + 4
    }
    *(float4*)(out + b * SEQ_L + t0 + tid * 4) = make_float4(a0, a1, a2, a3);
}

extern "C" void kernel_launch(void* const* d_in, const int* in_sizes, int n_in,
                              void* d_out, int out_size, void* d_ws, size_t ws_size,
                              hipStream_t stream) {
    const float* x    = (const float*)d_in[0];
    const float* A    = (const float*)d_in[1];
    const float* B    = (const float*)d_in[2];
    const float* C    = (const float*)d_in[3];
    const float* logd = (const float*)d_in[4];
    float* out = (float*)d_out;

    ssm_fir<<<NB * 16, 128, 0, stream>>>(x, A, B, C, logd, out);
}